// Round 7
// baseline (477.286 us; speedup 1.0000x reference)
//
#include <hip/hip_runtime.h>

// Unpool (conv_transpose2d, single-1 depthwise kernel), stride 2.
// in:  (8, 256, 112, 112) fp32;  out: (8, 256, 224, 224) fp32,
// out[:,:,::2,::2] = in, rest 0.
//
// v6: persistent grid-stride sweep that clones the poison-fill's structure
// (the one kernel counter-verified at ~6.3 TB/s): 1792 blocks x 256 threads
// (7 blocks/CU, 28 waves/CU), whole device advances ONE contiguous write
// frontier per step. Unit u = one float2 of input -> one float4 even-row
// data + one float4 odd-row zeros:
//   r = u/56, j = u%56
//   data:  out + 448r + 4j  = {x,0,y,0};  zeros: +224.
// Thread-stride T = 1792*256 = 458,752 units = 56*8192, so r,j are computed
// ONCE per thread; every subsequent address is thread-base + constant
// (fill-like near-zero VALU). 4 units per step (4 batched loads, then 8
// stores, zero-stores first - independent of loads). n = 12,845,056 =
// 7 steps * 4 * T exactly -> unguarded fast path (guarded tail kept for
// other shapes). Regular stores (nt measurably hurt: v3c). Every output
// element written exactly once (d_out is poisoned).

#define GRID   1792
#define BLOCK  256
#define TSTR   (GRID * BLOCK)        // 458,752 units per k-step
#define KU     4
#define STEP   (TSTR * KU)           // 1,835,008 units per outer step
#define ROWADV (448u * 8192u)        // output floats per k-step (T/56 rows)

__global__ __launch_bounds__(256) void unpool_sweep(
    const float2* __restrict__ in, float* __restrict__ out, unsigned n)
{
    const unsigned t  = blockIdx.x * blockDim.x + threadIdx.x;  // 0..TSTR-1
    const unsigned rt = t / 56u;
    const unsigned jt = t - rt * 56u;

    float* const bt = out + 448u * rt + 4u * jt;   // base for unit index t
    const float4 z4 = make_float4(0.f, 0.f, 0.f, 0.f);

    const unsigned nsteps = n / STEP;              // 7 for the bench shape

    for (unsigned i = 0; i < nsteps; ++i) {
        const unsigned q = i * KU;                 // 4i

        // 4 batched loads: each instruction contiguous across the wave,
        // whole device reads one contiguous window per instruction.
        const float2 v0 = in[(q + 0u) * TSTR + t];
        const float2 v1 = in[(q + 1u) * TSTR + t];
        const float2 v2 = in[(q + 2u) * TSTR + t];
        const float2 v3 = in[(q + 3u) * TSTR + t];

        float* b0 = bt + (q + 0u) * ROWADV;
        float* b1 = bt + (q + 1u) * ROWADV;
        float* b2 = bt + (q + 2u) * ROWADV;
        float* b3 = bt + (q + 3u) * ROWADV;

        // Odd-row zeros (independent of loads).
        *reinterpret_cast<float4*>(b0 + 224) = z4;
        *reinterpret_cast<float4*>(b1 + 224) = z4;
        *reinterpret_cast<float4*>(b2 + 224) = z4;
        *reinterpret_cast<float4*>(b3 + 224) = z4;

        // Even-row data.
        *reinterpret_cast<float4*>(b0) = make_float4(v0.x, 0.f, v0.y, 0.f);
        *reinterpret_cast<float4*>(b1) = make_float4(v1.x, 0.f, v1.y, 0.f);
        *reinterpret_cast<float4*>(b2) = make_float4(v2.x, 0.f, v2.y, 0.f);
        *reinterpret_cast<float4*>(b3) = make_float4(v3.x, 0.f, v3.y, 0.f);
    }

    // Guarded tail (not taken for the bench shape: n == nsteps*STEP).
    for (unsigned u = nsteps * STEP + t; u < n; u += TSTR) {
        const float2 v = in[u];
        const unsigned r = u / 56u, j = u - r * 56u;
        float* b = out + 448u * r + 4u * j;
        *reinterpret_cast<float4*>(b + 224) = z4;
        *reinterpret_cast<float4*>(b)       = make_float4(v.x, 0.f, v.y, 0.f);
    }
}

extern "C" void kernel_launch(void* const* d_in, const int* in_sizes, int n_in,
                              void* d_out, int out_size, void* d_ws, size_t ws_size,
                              hipStream_t stream)
{
    const float2* x = (const float2*)d_in[0];
    float* out      = (float*)d_out;

    // in_sizes[0] = 25,690,112 floats -> n = 12,845,056 float2 units.
    unsigned n = (unsigned)in_sizes[0] / 2u;

    unpool_sweep<<<GRID, BLOCK, 0, stream>>>(x, out, n);
}